// Round 1
// baseline (1013.884 us; speedup 1.0000x reference)
//
#include <hip/hip_runtime.h>
#include <cstdint>
#include <cstddef>

// Problem: B=128, L=196, E=2048, D=1024, A=1024, all fp32.
// Algebraic fusion:
//   dec_q[b,a] = sum_d dh[b,d] Wd[a,d] + bd[a]                  (K1)
//   u[b,e]     = sum_a dec_q[b,a] Wq[a,e]                       (K2)
//   c[b]       = sum_a bq[a] dec_q[b,a]                         (in K3)
//   energy     = tanh(x[b,l]·u[b] + c[b]); softmax over l (online)
//   y[b,e]     = sum_l w[b,l] x[b,l,e]                          (K3+merge)
//   context    = Wv y[b] + bv                                   (K5)

__global__ __launch_bounds__(256) void zero_f4(float* __restrict__ p, int n4) {
  int i = blockIdx.x * 256 + threadIdx.x;
  if (i < n4) reinterpret_cast<float4*>(p)[i] = make_float4(0.f, 0.f, 0.f, 0.f);
}

// out[m,n] += sum_{k in z-chunk} A[m,k]*B(k,n) via atomicAdd; bias added by z==0.
// A: [M][K] row-major. B: BNC ? [K][N] : [N][K]. Tile 128x128, 8x8 per thread.
template <bool BNC>
__global__ __launch_bounds__(256) void gemm_tn(
    const float* __restrict__ A, const float* __restrict__ Bm,
    const float* __restrict__ bias, float* __restrict__ out,
    int M, int N, int K, int kPerZ) {
  __shared__ float As[32][132];  // [kk][m], stride 132: 16B-aligned rows, 2-way-max banks
  __shared__ float Bs[32][132];  // [kk][n]
  const int t = threadIdx.x;
  const int tx = t & 15, ty = t >> 4;
  const int n0 = blockIdx.x * 128;
  const int m0 = blockIdx.y * 128;
  const int k0 = blockIdx.z * kPerZ;

  float acc[8][8];
#pragma unroll
  for (int i = 0; i < 8; ++i)
#pragma unroll
    for (int j = 0; j < 8; ++j) acc[i][j] = 0.f;

  for (int kb = k0; kb < k0 + kPerZ; kb += 32) {
    __syncthreads();
    {  // stage A: 128 m x 32 k, transpose into As[kk][m]
      int m = t >> 1, kq = (t & 1) * 16;
      const float* src = A + (size_t)(m0 + m) * K + (kb + kq);
      float4 v0 = *(const float4*)(src + 0);
      float4 v1 = *(const float4*)(src + 4);
      float4 v2 = *(const float4*)(src + 8);
      float4 v3 = *(const float4*)(src + 12);
      As[kq + 0][m] = v0.x; As[kq + 1][m] = v0.y; As[kq + 2][m] = v0.z; As[kq + 3][m] = v0.w;
      As[kq + 4][m] = v1.x; As[kq + 5][m] = v1.y; As[kq + 6][m] = v1.z; As[kq + 7][m] = v1.w;
      As[kq + 8][m] = v2.x; As[kq + 9][m] = v2.y; As[kq + 10][m] = v2.z; As[kq + 11][m] = v2.w;
      As[kq + 12][m] = v3.x; As[kq + 13][m] = v3.y; As[kq + 14][m] = v3.z; As[kq + 15][m] = v3.w;
    }
    if (BNC) {  // B[K][N]: direct copy rows
      int kk = t >> 3, nq = (t & 7) * 16;
      const float* src = Bm + (size_t)(kb + kk) * N + (n0 + nq);
      float4 v0 = *(const float4*)(src + 0);
      float4 v1 = *(const float4*)(src + 4);
      float4 v2 = *(const float4*)(src + 8);
      float4 v3 = *(const float4*)(src + 12);
      *(float4*)&Bs[kk][nq + 0] = v0;
      *(float4*)&Bs[kk][nq + 4] = v1;
      *(float4*)&Bs[kk][nq + 8] = v2;
      *(float4*)&Bs[kk][nq + 12] = v3;
    } else {  // B[N][K]: transpose like A
      int n = t >> 1, kq = (t & 1) * 16;
      const float* src = Bm + (size_t)(n0 + n) * K + (kb + kq);
      float4 v0 = *(const float4*)(src + 0);
      float4 v1 = *(const float4*)(src + 4);
      float4 v2 = *(const float4*)(src + 8);
      float4 v3 = *(const float4*)(src + 12);
      Bs[kq + 0][n] = v0.x; Bs[kq + 1][n] = v0.y; Bs[kq + 2][n] = v0.z; Bs[kq + 3][n] = v0.w;
      Bs[kq + 4][n] = v1.x; Bs[kq + 5][n] = v1.y; Bs[kq + 6][n] = v1.z; Bs[kq + 7][n] = v1.w;
      Bs[kq + 8][n] = v2.x; Bs[kq + 9][n] = v2.y; Bs[kq + 10][n] = v2.z; Bs[kq + 11][n] = v2.w;
      Bs[kq + 12][n] = v3.x; Bs[kq + 13][n] = v3.y; Bs[kq + 14][n] = v3.z; Bs[kq + 15][n] = v3.w;
    }
    __syncthreads();
#pragma unroll 4
    for (int kk = 0; kk < 32; ++kk) {
      float av[8], bv[8];
      *(float4*)&av[0] = *(const float4*)&As[kk][ty * 8 + 0];
      *(float4*)&av[4] = *(const float4*)&As[kk][ty * 8 + 4];
      *(float4*)&bv[0] = *(const float4*)&Bs[kk][tx * 8 + 0];
      *(float4*)&bv[4] = *(const float4*)&Bs[kk][tx * 8 + 4];
#pragma unroll
      for (int i = 0; i < 8; ++i)
#pragma unroll
        for (int j = 0; j < 8; ++j) acc[i][j] = fmaf(av[i], bv[j], acc[i][j]);
    }
  }
  const bool addb = (bias != nullptr) && (blockIdx.z == 0);
#pragma unroll
  for (int i = 0; i < 8; ++i) {
    int m = m0 + ty * 8 + i;
#pragma unroll
    for (int j = 0; j < 8; ++j) {
      int n = n0 + tx * 8 + j;
      float v = acc[i][j];
      if (addb) v += bias[n];
      atomicAdd(&out[(size_t)m * N + n], v);
    }
  }
}

// One streaming pass over x with online softmax. Grid: 512 blocks = (b, quarter of L).
// Block: 512 threads (8 waves). Wave w computes energy of row (lb+w); then all
// threads update their 4-float slice of the running y accumulator (x rows re-read
// from L1/L2 — they were just fetched for the dot).
__global__ __launch_bounds__(512) void attn_pass(
    const float* __restrict__ x,     // [B*L][E]
    const float* __restrict__ u,     // [B][E]
    const float* __restrict__ dec_q, // [B][A]
    const float* __restrict__ bq,    // [A]
    float* __restrict__ Yp,          // [B*4][E] unnormalized partial y
    float* __restrict__ ms) {        // [B*4][2] partial (m, s)
  const int L = 196, E = 2048, A = 1024, RPB = 49;
  __shared__ float uS[2048];
  __shared__ float eS[8];
  __shared__ float red[8];
  const int t = threadIdx.x;
  const int lane = t & 63, w = t >> 6;
  const int b = blockIdx.x >> 2, q = blockIdx.x & 3;
  const int l0 = q * RPB, lend = l0 + RPB;

  // stage u[b] into LDS
  *(float4*)&uS[t * 4] = *(const float4*)&u[(size_t)b * E + t * 4];

  // c[b] = bq . dec_q[b]  (block-redundant tiny dot)
  {
    const float* dq = dec_q + (size_t)b * A;
    float cp = fmaf(bq[t], dq[t], bq[t + 512] * dq[t + 512]);
    for (int off = 32; off; off >>= 1) cp += __shfl_xor(cp, off);
    if (lane == 0) red[w] = cp;
  }
  __syncthreads();
  const float cB = red[0] + red[1] + red[2] + red[3] + red[4] + red[5] + red[6] + red[7];

  float m = -1e30f, s = 0.f;
  float4 y = make_float4(0.f, 0.f, 0.f, 0.f);

  for (int lb = l0; lb < lend; lb += 8) {
    int l = lb + w;
    float e = -1e30f;
    if (l < lend) {  // wave-uniform branch
      const float* xr = x + ((size_t)b * L + l) * E;
      float d = 0.f;
#pragma unroll
      for (int i = 0; i < 8; ++i) {
        float4 xv = *(const float4*)(xr + lane * 4 + i * 256);
        float4 uv = *(const float4*)&uS[lane * 4 + i * 256];
        d = fmaf(xv.x, uv.x, d);
        d = fmaf(xv.y, uv.y, d);
        d = fmaf(xv.z, uv.z, d);
        d = fmaf(xv.w, uv.w, d);
      }
      for (int off = 32; off; off >>= 1) d += __shfl_xor(d, off);
      e = tanhf(d + cB);
    }
    if (lane == 0) eS[w] = e;
    __syncthreads();

    float ev[8];
#pragma unroll
    for (int j = 0; j < 8; ++j) ev[j] = eS[j];
    float bm = ev[0];
#pragma unroll
    for (int j = 1; j < 8; ++j) bm = fmaxf(bm, ev[j]);
    float mn = fmaxf(m, bm);
    float r = __expf(m - mn);  // m=-1e30 first pass -> r=0, no NaN
    s *= r;
    y.x *= r; y.y *= r; y.z *= r; y.w *= r;
#pragma unroll
    for (int j = 0; j < 8; ++j) {
      int l2 = lb + j;
      if (l2 < lend) {
        float wj = __expf(ev[j] - mn);
        s += wj;
        float4 xv = *(const float4*)(x + ((size_t)b * L + l2) * E + t * 4);
        y.x = fmaf(wj, xv.x, y.x);
        y.y = fmaf(wj, xv.y, y.y);
        y.z = fmaf(wj, xv.z, y.z);
        y.w = fmaf(wj, xv.w, y.w);
      }
    }
    m = mn;
    __syncthreads();
  }

  *(float4*)&Yp[(size_t)(b * 4 + q) * E + t * 4] = y;
  if (t == 0) {
    ms[(b * 4 + q) * 2 + 0] = m;
    ms[(b * 4 + q) * 2 + 1] = s;
  }
}

// Merge 4 partial (m,s,Y) per b into y[b] = softmax-weighted sum; also zero d_out
// so K5 can atomicAdd into it.
__global__ __launch_bounds__(256) void merge_y(
    const float* __restrict__ Yp, const float* __restrict__ ms,
    float* __restrict__ y, float* __restrict__ out) {
  const int E = 2048;
  int b = blockIdx.x, t = threadIdx.x;
  float mq[4], sq[4];
#pragma unroll
  for (int q = 0; q < 4; ++q) {
    mq[q] = ms[(b * 4 + q) * 2 + 0];
    sq[q] = ms[(b * 4 + q) * 2 + 1];
  }
  float M = fmaxf(fmaxf(mq[0], mq[1]), fmaxf(mq[2], mq[3]));
  float al[4], S = 0.f;
#pragma unroll
  for (int q = 0; q < 4; ++q) {
    al[q] = __expf(mq[q] - M);
    S = fmaf(sq[q], al[q], S);
  }
  float inv = 1.f / S;
#pragma unroll
  for (int half = 0; half < 2; ++half) {
    int pos = t * 4 + half * 1024;
    float4 a = make_float4(0.f, 0.f, 0.f, 0.f);
#pragma unroll
    for (int q = 0; q < 4; ++q) {
      float4 v = *(const float4*)&Yp[(size_t)(b * 4 + q) * E + pos];
      a.x = fmaf(al[q], v.x, a.x);
      a.y = fmaf(al[q], v.y, a.y);
      a.z = fmaf(al[q], v.z, a.z);
      a.w = fmaf(al[q], v.w, a.w);
    }
    a.x *= inv; a.y *= inv; a.z *= inv; a.w *= inv;
    *(float4*)&y[(size_t)b * E + pos] = a;
  }
  *(float4*)&out[(size_t)b * 1024 + t * 4] = make_float4(0.f, 0.f, 0.f, 0.f);
}

extern "C" void kernel_launch(void* const* d_in, const int* in_sizes, int n_in,
                              void* d_out, int out_size, void* d_ws, size_t ws_size,
                              hipStream_t stream) {
  const float* x  = (const float*)d_in[0];  // [128,196,2048]
  const float* dh = (const float*)d_in[1];  // [128,1024]
  const float* Wq = (const float*)d_in[2];  // [1024,2048]
  const float* bq = (const float*)d_in[3];  // [1024]
  const float* Wv = (const float*)d_in[4];  // [1024,2048]
  const float* bv = (const float*)d_in[5];  // [1024]
  const float* Wd = (const float*)d_in[6];  // [1024,1024]
  const float* bd = (const float*)d_in[7];  // [1024]
  float* out = (float*)d_out;               // [128,1024]
  float* ws = (float*)d_ws;

  float* dec_q = ws;            // 131072 floats
  float* u     = ws + 131072;   // 262144
  float* y     = ws + 393216;   // 262144
  float* Yp    = ws + 655360;   // 1048576
  float* msb   = ws + 1703936;  // 1024
  // total ~6.8 MB of d_ws

  // K0: zero dec_q and u (both accumulated via atomicAdd)
  zero_f4<<<dim3(384), 256, 0, stream>>>(ws, 98304);
  // K1: dec_q = dh @ Wd^T + bd   (M=128,N=1024,K=1024), B is [N][K]
  gemm_tn<false><<<dim3(8, 1, 32), 256, 0, stream>>>(dh, Wd, bd, dec_q, 128, 1024, 1024, 32);
  // K2: u = dec_q @ Wq           (M=128,N=2048,K=1024), B is [K][N]
  gemm_tn<true><<<dim3(16, 1, 16), 256, 0, stream>>>(dec_q, Wq, nullptr, u, 128, 2048, 1024, 64);
  // K3: streaming energy+online-softmax+partial y  (512 blocks: b x L-quarter)
  attn_pass<<<dim3(512), 512, 0, stream>>>(x, u, dec_q, bq, Yp, msb);
  // K4: merge partials -> y; zero out
  merge_y<<<dim3(128), 256, 0, stream>>>(Yp, msb, y, out);
  // K5: out = y @ Wv^T + bv      (M=128,N=1024,K=2048), B is [N][K]
  gemm_tn<false><<<dim3(8, 1, 32), 256, 0, stream>>>(y, Wv, bv, out, 128, 1024, 2048, 64);
}

// Round 5
// 382.293 us; speedup vs baseline: 2.6521x; 2.6521x over previous
//
#include <hip/hip_runtime.h>
#include <cstdint>
#include <cstddef>

// Problem: B=128, L=196, E=2048, D=1024, A=1024, all fp32.
// Algebraic fusion:
//   dec_q[b,a] = sum_d dh[b,d] Wd[a,d] + bd[a]                  (K1)
//   u[b,e]     = sum_a dec_q[b,a] Wq[a,e]                       (K2)
//   c[b]       = sum_a bq[a] dec_q[b,a]                         (in K3)
//   energy     = tanh(x[b,l]·u[b] + c[b]); softmax over l (online)
//   y[b,e]     = sum_l w[b,l] x[b,l,e]                          (K3+merge)
//   context    = Wv y[b] + bv                                   (K5)
//
// Round-4: resubmission (rounds 2-4 never acquired a GPU). Split-K GEMMs
// write per-z partial tiles to d_ws (plain stores) + a reduce kernel.
// Round-1's atomicAdd split-K serialized on contended cachelines
// (351 us/GEMM, VALUBusy 1%, WRITE_SIZE 134 MB).

// Deterministic split-K GEMM partial: part[z][m][n] = sum_{k in z-chunk} A[m,k]*B(k,n)
// A: [M][K] row-major. B: BNC ? [K][N] : [N][K]. Tile 128x128, 8x8 per thread.
template <bool BNC>
__global__ __launch_bounds__(256) void gemm_part(
    const float* __restrict__ A, const float* __restrict__ Bm,
    float* __restrict__ part, int M, int N, int K, int kPerZ) {
  __shared__ float As[32][132];  // [kk][m]
  __shared__ float Bs[32][132];  // [kk][n]
  const int t = threadIdx.x;
  const int tx = t & 15, ty = t >> 4;
  const int n0 = blockIdx.x * 128;
  const int m0 = blockIdx.y * 128;
  const int z  = blockIdx.z;
  const int k0 = z * kPerZ;

  float acc[8][8];
#pragma unroll
  for (int i = 0; i < 8; ++i)
#pragma unroll
    for (int j = 0; j < 8; ++j) acc[i][j] = 0.f;

  for (int kb = k0; kb < k0 + kPerZ; kb += 32) {
    __syncthreads();
    {  // stage A: 128 m x 32 k, transposed into As[kk][m]
      int m = t >> 1, kq = (t & 1) * 16;
      const float* src = A + (size_t)(m0 + m) * K + (kb + kq);
      float4 v0 = *(const float4*)(src + 0);
      float4 v1 = *(const float4*)(src + 4);
      float4 v2 = *(const float4*)(src + 8);
      float4 v3 = *(const float4*)(src + 12);
      As[kq + 0][m] = v0.x; As[kq + 1][m] = v0.y; As[kq + 2][m] = v0.z; As[kq + 3][m] = v0.w;
      As[kq + 4][m] = v1.x; As[kq + 5][m] = v1.y; As[kq + 6][m] = v1.z; As[kq + 7][m] = v1.w;
      As[kq + 8][m] = v2.x; As[kq + 9][m] = v2.y; As[kq + 10][m] = v2.z; As[kq + 11][m] = v2.w;
      As[kq + 12][m] = v3.x; As[kq + 13][m] = v3.y; As[kq + 14][m] = v3.z; As[kq + 15][m] = v3.w;
    }
    if (BNC) {  // B[K][N]: direct row copy
      int kk = t >> 3, nq = (t & 7) * 16;
      const float* src = Bm + (size_t)(kb + kk) * N + (n0 + nq);
      float4 v0 = *(const float4*)(src + 0);
      float4 v1 = *(const float4*)(src + 4);
      float4 v2 = *(const float4*)(src + 8);
      float4 v3 = *(const float4*)(src + 12);
      *(float4*)&Bs[kk][nq + 0] = v0;
      *(float4*)&Bs[kk][nq + 4] = v1;
      *(float4*)&Bs[kk][nq + 8] = v2;
      *(float4*)&Bs[kk][nq + 12] = v3;
    } else {  // B[N][K]: transpose like A
      int n = t >> 1, kq = (t & 1) * 16;
      const float* src = Bm + (size_t)(n0 + n) * K + (kb + kq);
      float4 v0 = *(const float4*)(src + 0);
      float4 v1 = *(const float4*)(src + 4);
      float4 v2 = *(const float4*)(src + 8);
      float4 v3 = *(const float4*)(src + 12);
      Bs[kq + 0][n] = v0.x; Bs[kq + 1][n] = v0.y; Bs[kq + 2][n] = v0.z; Bs[kq + 3][n] = v0.w;
      Bs[kq + 4][n] = v1.x; Bs[kq + 5][n] = v1.y; Bs[kq + 6][n] = v1.z; Bs[kq + 7][n] = v1.w;
      Bs[kq + 8][n] = v2.x; Bs[kq + 9][n] = v2.y; Bs[kq + 10][n] = v2.z; Bs[kq + 11][n] = v2.w;
      Bs[kq + 12][n] = v3.x; Bs[kq + 13][n] = v3.y; Bs[kq + 14][n] = v3.z; Bs[kq + 15][n] = v3.w;
    }
    __syncthreads();
#pragma unroll 4
    for (int kk = 0; kk < 32; ++kk) {
      float av[8], bv[8];
      *(float4*)&av[0] = *(const float4*)&As[kk][ty * 8 + 0];
      *(float4*)&av[4] = *(const float4*)&As[kk][ty * 8 + 4];
      *(float4*)&bv[0] = *(const float4*)&Bs[kk][tx * 8 + 0];
      *(float4*)&bv[4] = *(const float4*)&Bs[kk][tx * 8 + 4];
#pragma unroll
      for (int i = 0; i < 8; ++i)
#pragma unroll
        for (int j = 0; j < 8; ++j) acc[i][j] = fmaf(av[i], bv[j], acc[i][j]);
    }
  }
  float* dst = part + (size_t)z * M * N;
#pragma unroll
  for (int i = 0; i < 8; ++i) {
    int m = m0 + ty * 8 + i;
    float4 lo = make_float4(acc[i][0], acc[i][1], acc[i][2], acc[i][3]);
    float4 hi = make_float4(acc[i][4], acc[i][5], acc[i][6], acc[i][7]);
    *(float4*)&dst[(size_t)m * N + n0 + tx * 8 + 0] = lo;
    *(float4*)&dst[(size_t)m * N + n0 + tx * 8 + 4] = hi;
  }
}

// out[i] = sum_z part[z][i] (+ bias broadcast over rows). float4 per thread.
__global__ __launch_bounds__(256) void reduce_part(
    const float* __restrict__ part, const float* __restrict__ bias,
    float* __restrict__ out, int MN, int N, int Z) {
  int i = blockIdx.x * 256 + threadIdx.x;  // float4 index
  if (i * 4 >= MN) return;
  float4 a = make_float4(0.f, 0.f, 0.f, 0.f);
  for (int z = 0; z < Z; ++z) {
    float4 v = *(const float4*)&part[(size_t)z * MN + i * 4];
    a.x += v.x; a.y += v.y; a.z += v.z; a.w += v.w;
  }
  if (bias) {
    int n = (i * 4) % N;
    float4 bb = *(const float4*)&bias[n];
    a.x += bb.x; a.y += bb.y; a.z += bb.z; a.w += bb.w;
  }
  *(float4*)&out[(size_t)i * 4] = a;
}

// One streaming pass over x with online softmax. Grid: 512 blocks = (b, quarter of L).
__global__ __launch_bounds__(512) void attn_pass(
    const float* __restrict__ x,     // [B*L][E]
    const float* __restrict__ u,     // [B][E]
    const float* __restrict__ dec_q, // [B][A]
    const float* __restrict__ bq,    // [A]
    float* __restrict__ Yp,          // [B*4][E] unnormalized partial y
    float* __restrict__ ms) {        // [B*4][2] partial (m, s)
  const int L = 196, E = 2048, A = 1024, RPB = 49;
  __shared__ float uS[2048];
  __shared__ float eS[8];
  __shared__ float red[8];
  const int t = threadIdx.x;
  const int lane = t & 63, w = t >> 6;
  const int b = blockIdx.x >> 2, q = blockIdx.x & 3;
  const int l0 = q * RPB, lend = l0 + RPB;

  *(float4*)&uS[t * 4] = *(const float4*)&u[(size_t)b * E + t * 4];

  {  // c[b] = bq . dec_q[b]
    const float* dq = dec_q + (size_t)b * A;
    float cp = fmaf(bq[t], dq[t], bq[t + 512] * dq[t + 512]);
    for (int off = 32; off; off >>= 1) cp += __shfl_xor(cp, off);
    if (lane == 0) red[w] = cp;
  }
  __syncthreads();
  const float cB = red[0] + red[1] + red[2] + red[3] + red[4] + red[5] + red[6] + red[7];

  float m = -1e30f, s = 0.f;
  float4 y = make_float4(0.f, 0.f, 0.f, 0.f);

  for (int lb = l0; lb < lend; lb += 8) {
    int l = lb + w;
    float e = -1e30f;
    if (l < lend) {  // wave-uniform branch
      const float* xr = x + ((size_t)b * L + l) * E;
      float d = 0.f;
#pragma unroll
      for (int i = 0; i < 8; ++i) {
        float4 xv = *(const float4*)(xr + lane * 4 + i * 256);
        float4 uv = *(const float4*)&uS[lane * 4 + i * 256];
        d = fmaf(xv.x, uv.x, d);
        d = fmaf(xv.y, uv.y, d);
        d = fmaf(xv.z, uv.z, d);
        d = fmaf(xv.w, uv.w, d);
      }
      for (int off = 32; off; off >>= 1) d += __shfl_xor(d, off);
      e = tanhf(d + cB);
    }
    if (lane == 0) eS[w] = e;
    __syncthreads();

    float ev[8];
#pragma unroll
    for (int j = 0; j < 8; ++j) ev[j] = eS[j];
    float bm = ev[0];
#pragma unroll
    for (int j = 1; j < 8; ++j) bm = fmaxf(bm, ev[j]);
    float mn = fmaxf(m, bm);
    float r = __expf(m - mn);  // m=-1e30 first pass -> r=0, no NaN
    s *= r;
    y.x *= r; y.y *= r; y.z *= r; y.w *= r;
#pragma unroll
    for (int j = 0; j < 8; ++j) {
      int l2 = lb + j;
      if (l2 < lend) {
        float wj = __expf(ev[j] - mn);
        s += wj;
        float4 xv = *(const float4*)(x + ((size_t)b * L + l2) * E + t * 4);
        y.x = fmaf(wj, xv.x, y.x);
        y.y = fmaf(wj, xv.y, y.y);
        y.z = fmaf(wj, xv.z, y.z);
        y.w = fmaf(wj, xv.w, y.w);
      }
    }
    m = mn;
    __syncthreads();
  }

  *(float4*)&Yp[(size_t)(b * 4 + q) * E + t * 4] = y;
  if (t == 0) {
    ms[(b * 4 + q) * 2 + 0] = m;
    ms[(b * 4 + q) * 2 + 1] = s;
  }
}

// Merge 4 partial (m,s,Y) per b into y[b].
__global__ __launch_bounds__(256) void merge_y(
    const float* __restrict__ Yp, const float* __restrict__ ms,
    float* __restrict__ y) {
  const int E = 2048;
  int b = blockIdx.x, t = threadIdx.x;
  float mq[4], sq[4];
#pragma unroll
  for (int q = 0; q < 4; ++q) {
    mq[q] = ms[(b * 4 + q) * 2 + 0];
    sq[q] = ms[(b * 4 + q) * 2 + 1];
  }
  float M = fmaxf(fmaxf(mq[0], mq[1]), fmaxf(mq[2], mq[3]));
  float al[4], S = 0.f;
#pragma unroll
  for (int q = 0; q < 4; ++q) {
    al[q] = __expf(mq[q] - M);
    S = fmaf(sq[q], al[q], S);
  }
  float inv = 1.f / S;
#pragma unroll
  for (int half = 0; half < 2; ++half) {
    int pos = t * 4 + half * 1024;
    float4 a = make_float4(0.f, 0.f, 0.f, 0.f);
#pragma unroll
    for (int q = 0; q < 4; ++q) {
      float4 v = *(const float4*)&Yp[(size_t)(b * 4 + q) * E + pos];
      a.x = fmaf(al[q], v.x, a.x);
      a.y = fmaf(al[q], v.y, a.y);
      a.z = fmaf(al[q], v.z, a.z);
      a.w = fmaf(al[q], v.w, a.w);
    }
    a.x *= inv; a.y *= inv; a.z *= inv; a.w *= inv;
    *(float4*)&y[(size_t)b * E + pos] = a;
  }
}

extern "C" void kernel_launch(void* const* d_in, const int* in_sizes, int n_in,
                              void* d_out, int out_size, void* d_ws, size_t ws_size,
                              hipStream_t stream) {
  const float* x  = (const float*)d_in[0];  // [128,196,2048]
  const float* dh = (const float*)d_in[1];  // [128,1024]
  const float* Wq = (const float*)d_in[2];  // [1024,2048]
  const float* bq = (const float*)d_in[3];  // [1024]
  const float* Wv = (const float*)d_in[4];  // [1024,2048]
  const float* bv = (const float*)d_in[5];  // [1024]
  const float* Wd = (const float*)d_in[6];  // [1024,1024]
  const float* bd = (const float*)d_in[7];  // [1024]
  float* out = (float*)d_out;               // [128,1024]
  float* ws = (float*)d_ws;

  float* dec_q = ws;            // 131072 floats (0.5 MB)
  float* u     = ws + 131072;   // 262144 (1 MB)
  float* y     = ws + 393216;   // 262144 (1 MB)
  float* Yp    = ws + 655360;   // 1048576 (4 MB)
  float* msb   = ws + 1703936;  // 1024
  float* part  = ws + 1705984;  // 4194304 floats (16 MB), reused by all 3 GEMMs
  // total ~23 MB of d_ws

  // K1: dec_q = dh @ Wd^T + bd   (M=128,N=1024,K=1024), B is [N][K], Z=32
  gemm_part<false><<<dim3(8, 1, 32), 256, 0, stream>>>(dh, Wd, part, 128, 1024, 1024, 32);
  reduce_part<<<dim3(128), 256, 0, stream>>>(part, bd, dec_q, 131072, 1024, 32);
  // K2: u = dec_q @ Wq           (M=128,N=2048,K=1024), B is [K][N], Z=16
  gemm_part<true><<<dim3(16, 1, 16), 256, 0, stream>>>(dec_q, Wq, part, 128, 2048, 1024, 64);
  reduce_part<<<dim3(256), 256, 0, stream>>>(part, nullptr, u, 262144, 2048, 16);
  // K3: streaming energy + online-softmax + partial y  (512 blocks: b x L-quarter)
  attn_pass<<<dim3(512), 512, 0, stream>>>(x, u, dec_q, bq, Yp, msb);
  // K4: merge partials -> y
  merge_y<<<dim3(128), 256, 0, stream>>>(Yp, msb, y);
  // K5: out = y @ Wv^T + bv      (M=128,N=1024,K=2048), B is [N][K], Z=32
  gemm_part<false><<<dim3(8, 1, 32), 256, 0, stream>>>(y, Wv, part, 128, 1024, 2048, 64);
  reduce_part<<<dim3(128), 256, 0, stream>>>(part, bv, out, 131072, 1024, 32);
}

// Round 6
// 368.845 us; speedup vs baseline: 2.7488x; 1.0365x over previous
//
#include <hip/hip_runtime.h>
#include <cstdint>
#include <cstddef>

// Problem: B=128, L=196, E=2048, D=1024, A=1024, all fp32.
// Algebraic fusion:
//   dec_q[b,a] = sum_d dh[b,d] Wd[a,d] + bd[a]                  (K1)
//   u[b,e]     = sum_a dec_q[b,a] Wq[a,e]                       (K2)
//   c[b]       = sum_a bq[a] dec_q[b,a]                         (in K3)
//   energy     = tanh(x[b,l]·u[b] + c[b]); softmax over l
//   y[b,e]     = sum_l w[b,l] x[b,l,e]                          (K3+merge)
//   context    = Wv y[b] + bv                                   (K5)
//
// Round-6: (1) tanh bounds energy to [-1,1] -> exp() needs NO max
// subtraction -> attn_pass is a single register-resident streaming pass
// over x (one HBM read, no re-read, no barriers in main loop).
// (2) GEMM tile 128x64 -> 512 blocks = 2/CU (was 1/CU, 1 wave/SIMD).

// Deterministic split-K GEMM partial: part[z][m][n] = sum_{k in z-chunk} A[m,k]*B(k,n)
// A: [M][K] row-major. B: BNC ? [K][N] : [N][K]. Tile 128x64, 4x8 per thread.
template <bool BNC>
__global__ __launch_bounds__(256) void gemm_part(
    const float* __restrict__ A, const float* __restrict__ Bm,
    float* __restrict__ part, int M, int N, int K, int kPerZ) {
  __shared__ float As[32][132];  // [kk][m], pad 132
  __shared__ float Bs[32][68];   // [kk][n], pad 68
  const int t = threadIdx.x;
  const int tx = t & 7, ty = t >> 3;   // tx: 8 col-groups of 8, ty: 32 row-groups of 4
  const int n0 = blockIdx.x * 64;
  const int m0 = blockIdx.y * 128;     // M=128 -> always 0
  const int z  = blockIdx.z;
  const int k0 = z * kPerZ;

  float acc[4][8];
#pragma unroll
  for (int i = 0; i < 4; ++i)
#pragma unroll
    for (int j = 0; j < 8; ++j) acc[i][j] = 0.f;

  for (int kb = k0; kb < k0 + kPerZ; kb += 32) {
    __syncthreads();
    {  // stage A: 128 m x 32 k, transposed into As[kk][m]
      int m = t >> 1, kq = (t & 1) * 16;
      const float* src = A + (size_t)(m0 + m) * K + (kb + kq);
      float4 v0 = *(const float4*)(src + 0);
      float4 v1 = *(const float4*)(src + 4);
      float4 v2 = *(const float4*)(src + 8);
      float4 v3 = *(const float4*)(src + 12);
      As[kq + 0][m] = v0.x; As[kq + 1][m] = v0.y; As[kq + 2][m] = v0.z; As[kq + 3][m] = v0.w;
      As[kq + 4][m] = v1.x; As[kq + 5][m] = v1.y; As[kq + 6][m] = v1.z; As[kq + 7][m] = v1.w;
      As[kq + 8][m] = v2.x; As[kq + 9][m] = v2.y; As[kq + 10][m] = v2.z; As[kq + 11][m] = v2.w;
      As[kq + 12][m] = v3.x; As[kq + 13][m] = v3.y; As[kq + 14][m] = v3.z; As[kq + 15][m] = v3.w;
    }
    if (BNC) {  // B[K][N]: direct row copy, 32 kk x 64 n
      int kk = t >> 3, nq = (t & 7) * 8;
      const float* src = Bm + (size_t)(kb + kk) * N + (n0 + nq);
      float4 v0 = *(const float4*)(src + 0);
      float4 v1 = *(const float4*)(src + 4);
      *(float4*)&Bs[kk][nq + 0] = v0;
      *(float4*)&Bs[kk][nq + 4] = v1;
    } else {  // B[N][K]: transpose, 64 n x 32 k
      int n = t >> 2, kq = (t & 3) * 8;
      const float* src = Bm + (size_t)(n0 + n) * K + (kb + kq);
      float4 v0 = *(const float4*)(src + 0);
      float4 v1 = *(const float4*)(src + 4);
      Bs[kq + 0][n] = v0.x; Bs[kq + 1][n] = v0.y; Bs[kq + 2][n] = v0.z; Bs[kq + 3][n] = v0.w;
      Bs[kq + 4][n] = v1.x; Bs[kq + 5][n] = v1.y; Bs[kq + 6][n] = v1.z; Bs[kq + 7][n] = v1.w;
    }
    __syncthreads();
#pragma unroll 4
    for (int kk = 0; kk < 32; ++kk) {
      float av[4], bv[8];
      *(float4*)&av[0] = *(const float4*)&As[kk][ty * 4];
      *(float4*)&bv[0] = *(const float4*)&Bs[kk][tx * 8 + 0];
      *(float4*)&bv[4] = *(const float4*)&Bs[kk][tx * 8 + 4];
#pragma unroll
      for (int i = 0; i < 4; ++i)
#pragma unroll
        for (int j = 0; j < 8; ++j) acc[i][j] = fmaf(av[i], bv[j], acc[i][j]);
    }
  }
  float* dst = part + (size_t)z * M * N;
#pragma unroll
  for (int i = 0; i < 4; ++i) {
    int m = m0 + ty * 4 + i;
    float4 lo = make_float4(acc[i][0], acc[i][1], acc[i][2], acc[i][3]);
    float4 hi = make_float4(acc[i][4], acc[i][5], acc[i][6], acc[i][7]);
    *(float4*)&dst[(size_t)m * N + n0 + tx * 8 + 0] = lo;
    *(float4*)&dst[(size_t)m * N + n0 + tx * 8 + 4] = hi;
  }
}

// out[i] = sum_z part[z][i] (+ bias broadcast over rows). float4 per thread.
__global__ __launch_bounds__(256) void reduce_part(
    const float* __restrict__ part, const float* __restrict__ bias,
    float* __restrict__ out, int MN, int N, int Z) {
  int i = blockIdx.x * 256 + threadIdx.x;  // float4 index
  if (i * 4 >= MN) return;
  float4 a = make_float4(0.f, 0.f, 0.f, 0.f);
  for (int z = 0; z < Z; ++z) {
    float4 v = *(const float4*)&part[(size_t)z * MN + i * 4];
    a.x += v.x; a.y += v.y; a.z += v.z; a.w += v.w;
  }
  if (bias) {
    int n = (i * 4) % N;
    float4 bb = *(const float4*)&bias[n];
    a.x += bb.x; a.y += bb.y; a.z += bb.z; a.w += bb.w;
  }
  *(float4*)&out[(size_t)i * 4] = a;
}

// Single streaming pass over x. tanh-bounded energies -> exp() without max
// tracking. Each wave owns rows l0+w, l0+w+4, ...; the full 2048-float row
// lives in registers (32 floats/lane); y accumulates in registers.
// Grid: 512 blocks = (b, quarter of L); 256 threads = 4 waves.
__global__ __launch_bounds__(256) void attn_pass(
    const float* __restrict__ x,     // [B*L][E]
    const float* __restrict__ u,     // [B][E]
    const float* __restrict__ dec_q, // [B][A]
    const float* __restrict__ bq,    // [A]
    float* __restrict__ Yp,          // [B*4][E] unnormalized partial y
    float* __restrict__ ss) {        // [B*4] partial sum of exp
  const int L = 196, E = 2048, A = 1024, RPB = 49;
  __shared__ float yS[4][2048];  // 32 KB wave partials
  __shared__ float red[4];
  __shared__ float sred[4];
  const int t = threadIdx.x;
  const int lane = t & 63, w = t >> 6;
  const int b = blockIdx.x >> 2, q = blockIdx.x & 3;
  const int l0 = q * RPB;

  {  // c[b] = bq . dec_q[b]  (block-redundant tiny dot over 1024)
    const float* dq = dec_q + (size_t)b * A;
    float cp = 0.f;
#pragma unroll
    for (int j = 0; j < 4; ++j) cp = fmaf(bq[t + j * 256], dq[t + j * 256], cp);
    for (int off = 32; off; off >>= 1) cp += __shfl_xor(cp, off);
    if (lane == 0) red[w] = cp;
  }
  __syncthreads();
  const float cB = red[0] + red[1] + red[2] + red[3];

  // u[b] slice in registers: lane covers floats lane*4 + i*256, i=0..7
  float4 ur[8];
  const float* ub = u + (size_t)b * E;
#pragma unroll
  for (int i = 0; i < 8; ++i) ur[i] = *(const float4*)(ub + lane * 4 + i * 256);

  float4 y[8];
#pragma unroll
  for (int i = 0; i < 8; ++i) y[i] = make_float4(0.f, 0.f, 0.f, 0.f);
  float s = 0.f;

  for (int l = l0 + w; l < l0 + RPB; l += 4) {  // wave-private, no barriers
    const float* xr = x + ((size_t)b * L + l) * E;
    float4 xv[8];
#pragma unroll
    for (int i = 0; i < 8; ++i) xv[i] = *(const float4*)(xr + lane * 4 + i * 256);
    float d = 0.f;
#pragma unroll
    for (int i = 0; i < 8; ++i) {
      d = fmaf(xv[i].x, ur[i].x, d);
      d = fmaf(xv[i].y, ur[i].y, d);
      d = fmaf(xv[i].z, ur[i].z, d);
      d = fmaf(xv[i].w, ur[i].w, d);
    }
    for (int off = 32; off; off >>= 1) d += __shfl_xor(d, off);
    float wj = __expf(tanhf(d + cB));  // e in [-1,1] -> exp in [0.37,2.72]
    s += wj;
#pragma unroll
    for (int i = 0; i < 8; ++i) {
      y[i].x = fmaf(wj, xv[i].x, y[i].x);
      y[i].y = fmaf(wj, xv[i].y, y[i].y);
      y[i].z = fmaf(wj, xv[i].z, y[i].z);
      y[i].w = fmaf(wj, xv[i].w, y[i].w);
    }
  }

  // wave partial -> LDS, then 4-wave block reduction
#pragma unroll
  for (int i = 0; i < 8; ++i) *(float4*)&yS[w][lane * 4 + i * 256] = y[i];
  if (lane == 0) sred[w] = s;
  __syncthreads();

#pragma unroll
  for (int h = 0; h < 2; ++h) {
    int pos = t * 4 + h * 1024;
    float4 a0 = *(const float4*)&yS[0][pos];
    float4 a1 = *(const float4*)&yS[1][pos];
    float4 a2 = *(const float4*)&yS[2][pos];
    float4 a3 = *(const float4*)&yS[3][pos];
    float4 a = make_float4(a0.x + a1.x + a2.x + a3.x, a0.y + a1.y + a2.y + a3.y,
                           a0.z + a1.z + a2.z + a3.z, a0.w + a1.w + a2.w + a3.w);
    *(float4*)&Yp[(size_t)blockIdx.x * E + pos] = a;
  }
  if (t == 0) ss[blockIdx.x] = sred[0] + sred[1] + sred[2] + sred[3];
}

// Merge 4 partial (Y, s) per b into y[b] (no max: plain sums).
__global__ __launch_bounds__(256) void merge_y(
    const float* __restrict__ Yp, const float* __restrict__ ss,
    float* __restrict__ y) {
  const int E = 2048;
  int b = blockIdx.x, t = threadIdx.x;
  float S = ss[b * 4 + 0] + ss[b * 4 + 1] + ss[b * 4 + 2] + ss[b * 4 + 3];
  float inv = 1.f / S;
#pragma unroll
  for (int h = 0; h < 2; ++h) {
    int pos = t * 4 + h * 1024;
    float4 a = make_float4(0.f, 0.f, 0.f, 0.f);
#pragma unroll
    for (int qq = 0; qq < 4; ++qq) {
      float4 v = *(const float4*)&Yp[(size_t)(b * 4 + qq) * E + pos];
      a.x += v.x; a.y += v.y; a.z += v.z; a.w += v.w;
    }
    a.x *= inv; a.y *= inv; a.z *= inv; a.w *= inv;
    *(float4*)&y[(size_t)b * E + pos] = a;
  }
}

extern "C" void kernel_launch(void* const* d_in, const int* in_sizes, int n_in,
                              void* d_out, int out_size, void* d_ws, size_t ws_size,
                              hipStream_t stream) {
  const float* x  = (const float*)d_in[0];  // [128,196,2048]
  const float* dh = (const float*)d_in[1];  // [128,1024]
  const float* Wq = (const float*)d_in[2];  // [1024,2048]
  const float* bq = (const float*)d_in[3];  // [1024]
  const float* Wv = (const float*)d_in[4];  // [1024,2048]
  const float* bv = (const float*)d_in[5];  // [1024]
  const float* Wd = (const float*)d_in[6];  // [1024,1024]
  const float* bd = (const float*)d_in[7];  // [1024]
  float* out = (float*)d_out;               // [128,1024]
  float* ws = (float*)d_ws;

  float* dec_q = ws;            // 131072 floats (0.5 MB)
  float* u     = ws + 131072;   // 262144 (1 MB)
  float* y     = ws + 393216;   // 262144 (1 MB)
  float* Yp    = ws + 655360;   // 1048576 (4 MB)
  float* ssb   = ws + 1703936;  // 512
  float* part  = ws + 1705984;  // 4194304 floats (16 MB), reused by all 3 GEMMs
  // total ~23.6 MB of d_ws

  // K1: dec_q = dh @ Wd^T + bd   (M=128,N=1024,K=1024), B is [N][K], Z=32
  gemm_part<false><<<dim3(16, 1, 32), 256, 0, stream>>>(dh, Wd, part, 128, 1024, 1024, 32);
  reduce_part<<<dim3(128), 256, 0, stream>>>(part, bd, dec_q, 131072, 1024, 32);
  // K2: u = dec_q @ Wq           (M=128,N=2048,K=1024), B is [K][N], Z=16
  gemm_part<true><<<dim3(32, 1, 16), 256, 0, stream>>>(dec_q, Wq, part, 128, 2048, 1024, 64);
  reduce_part<<<dim3(256), 256, 0, stream>>>(part, nullptr, u, 262144, 2048, 16);
  // K3: single streaming pass: energy + exp + register-resident y partials
  attn_pass<<<dim3(512), 256, 0, stream>>>(x, u, dec_q, bq, Yp, ssb);
  // K4: merge partials -> y
  merge_y<<<dim3(128), 256, 0, stream>>>(Yp, ssb, y);
  // K5: out = y @ Wv^T + bv      (M=128,N=1024,K=2048), B is [N][K], Z=32
  gemm_part<false><<<dim3(16, 1, 32), 256, 0, stream>>>(y, Wv, part, 128, 1024, 2048, 64);
  reduce_part<<<dim3(128), 256, 0, stream>>>(part, bv, out, 131072, 1024, 32);
}